// Round 6
// baseline (206.292 us; speedup 1.0000x reference)
//
#include <hip/hip_runtime.h>

typedef __attribute__((ext_vector_type(8))) short short8;
typedef __attribute__((ext_vector_type(4))) float floatx4;

#define HW 4096
#define CIN 256
#define CK 128
#define COUT 256
#define NB 4
#define BN_EPS 1e-5f
// (1/sqrt(128)) * log2(e), folded into Q at projection time -> P = exp2(S)
#define SC2 0.12751744526f

#define MFMA(a, b, c) __builtin_amdgcn_mfma_f32_16x16x32_bf16((a), (b), (c), 0, 0, 0)

__device__ __forceinline__ unsigned short f2bf(float f) {
  union { float f; unsigned u; } v; v.f = f;
  unsigned r = v.u + 0x7fffu + ((v.u >> 16) & 1u);  // RNE
  return (unsigned short)(r >> 16);
}

__device__ __forceinline__ short8 pack8(const float* p) {
  short8 r;
#pragma unroll
  for (int i = 0; i < 8; ++i) r[i] = (short)f2bf(p[i]);
  return r;
}

// ---------------------------------------------------------------------------
// Kernel 0: pre-pack weights as bf16 in MFMA A-fragment order (coalesced
// 16B/lane loads in proj/outproj). Layouts as in round 5.
// ---------------------------------------------------------------------------
__global__ __launch_bounds__(256) void prep_kernel(
    const float* __restrict__ wq, const float* __restrict__ wk,
    const float* __restrict__ wv, const float* __restrict__ wo,
    unsigned short* __restrict__ WqP, unsigned short* __restrict__ WkvP,
    unsigned short* __restrict__ WoP)
{
  const int t = blockIdx.x * 256 + threadIdx.x;  // 0..16383
  float tmp[8];
  if (t < 4096) {
    const int lane = t & 63, mt = (t >> 6) & 1, wave = (t >> 7) & 3, ks = t >> 9;
    const int lane16 = lane & 15, quad = lane >> 4;
    const int o = wave * 32 + mt * 16 + lane16;
    const float* src = wq + (size_t)o * CIN + ks * 32 + quad * 8;
    *(float4*)tmp = *(const float4*)src;
    *(float4*)(tmp + 4) = *(const float4*)(src + 4);
    *(short8*)&WqP[(size_t)t * 8] = pack8(tmp);
  } else if (t < 12288) {
    const int u = t - 4096;
    const int lane = u & 63, mt = (u >> 6) & 3, wave = (u >> 8) & 3, ks = u >> 10;
    const int lane16 = lane & 15, quad = lane >> 4;
    const int o = wave * 64 + mt * 16 + lane16;
    const float* row = (o < 128) ? wk + (size_t)o * CIN : wv + (size_t)(o - 128) * CIN;
    const float* src = row + ks * 32 + quad * 8;
    *(float4*)tmp = *(const float4*)src;
    *(float4*)(tmp + 4) = *(const float4*)(src + 4);
    *(short8*)&WkvP[(size_t)u * 8] = pack8(tmp);
  } else {
    const int u = t - 12288;
    const int lane = u & 63, mt = (u >> 6) & 3, wave = (u >> 8) & 3, ks = u >> 10;
    const int lane16 = lane & 15, quad = lane >> 4;
    const int o = wave * 64 + mt * 16 + lane16;
    const float* src = wo + (size_t)o * CK + ks * 32 + quad * 8;
    *(float4*)tmp = *(const float4*)src;
    *(float4*)(tmp + 4) = *(const float4*)(src + 4);
    *(short8*)&WoP[(size_t)u * 8] = pack8(tmp);
  }
}

// ---------------------------------------------------------------------------
// Kernel 1: projections. grid (64, 4, 2), block 256. (unchanged, round 5)
// ---------------------------------------------------------------------------
__global__ __launch_bounds__(256) void proj_kernel(
    const float* __restrict__ x_enc, const float* __restrict__ x_dec,
    const unsigned short* __restrict__ WqP, const unsigned short* __restrict__ WkvP,
    const float* __restrict__ bq, const float* __restrict__ gq,
    const float* __restrict__ betaq, const float* __restrict__ mq,
    const float* __restrict__ vq,
    const float* __restrict__ bk, const float* __restrict__ gk,
    const float* __restrict__ betak, const float* __restrict__ mk,
    const float* __restrict__ vk, const float* __restrict__ bv,
    unsigned short* __restrict__ Qb, unsigned short* __restrict__ Kb,
    unsigned short* __restrict__ Vt)
{
  const int tid = threadIdx.x;
  const int pt = blockIdx.x;
  const int b  = blockIdx.y;
  const int pj = blockIdx.z;

  const float* X = (pj == 0) ? x_dec : x_enc;

  __shared__ float xF[64 * 68];
  __shared__ unsigned short xT[64 * 264];

  const float* Xs = X + (size_t)b * CIN * HW + (size_t)pt * 64;
#pragma unroll
  for (int qtr = 0; qtr < 4; ++qtr) {
    if (qtr) __syncthreads();
    {
      const int c = tid >> 2;
      const int p0 = (tid & 3) * 16;
      const float* src = Xs + (size_t)(qtr * 64 + c) * HW + p0;
#pragma unroll
      for (int j = 0; j < 4; ++j)
        *(float4*)&xF[c * 68 + p0 + j * 4] = *(const float4*)(src + j * 4);
    }
    __syncthreads();
    {
      const int p = tid & 63;
      const int cb = tid >> 6;
#pragma unroll
      for (int jj = 0; jj < 2; ++jj) {
        const int c0 = (jj * 4 + cb) * 8;
        float t[8];
#pragma unroll
        for (int u = 0; u < 8; ++u) t[u] = xF[(c0 + u) * 68 + p];
        *(short8*)&xT[p * 264 + qtr * 64 + c0] = pack8(t);
      }
    }
  }
  __syncthreads();

  const int wave = tid >> 6;
  const int lane = tid & 63;
  const int lane16 = lane & 15;
  const int quad = lane >> 4;

  if (pj == 0) {
    floatx4 acc[2][4];
#pragma unroll
    for (int mt = 0; mt < 2; ++mt)
#pragma unroll
      for (int nf = 0; nf < 4; ++nf) acc[mt][nf] = (floatx4){0.f, 0.f, 0.f, 0.f};

#pragma unroll
    for (int ks = 0; ks < 8; ++ks) {
      short8 af[2];
#pragma unroll
      for (int mt = 0; mt < 2; ++mt)
        af[mt] = *(const short8*)&WqP[(size_t)((((ks * 4 + wave) * 2 + mt) * 64) + lane) * 8];
#pragma unroll
      for (int nf = 0; nf < 4; ++nf) {
        const short8 bf = *(const short8*)&xT[(nf * 16 + lane16) * 264 + ks * 32 + quad * 8];
#pragma unroll
        for (int mt = 0; mt < 2; ++mt) acc[mt][nf] = MFMA(af[mt], bf, acc[mt][nf]);
      }
    }

    float sc[2][4], off[2][4];
#pragma unroll
    for (int mt = 0; mt < 2; ++mt)
#pragma unroll
      for (int r = 0; r < 4; ++r) {
        const int o = wave * 32 + mt * 16 + quad * 4 + r;
        const float s = gq[o] * rsqrtf(vq[o] + BN_EPS) * SC2;
        sc[mt][r] = s;
        off[mt][r] = (bq[o] - mq[o]) * s + betaq[o] * SC2;
      }
#pragma unroll
    for (int nf = 0; nf < 4; ++nf) {
      const size_t prow = ((size_t)b * HW + pt * 64 + nf * 16 + lane16) * CK;
#pragma unroll
      for (int mt = 0; mt < 2; ++mt) {
        ushort4 pk;
        pk.x = f2bf(fmaxf(acc[mt][nf][0] * sc[mt][0] + off[mt][0], 0.f));
        pk.y = f2bf(fmaxf(acc[mt][nf][1] * sc[mt][1] + off[mt][1], 0.f));
        pk.z = f2bf(fmaxf(acc[mt][nf][2] * sc[mt][2] + off[mt][2], 0.f));
        pk.w = f2bf(fmaxf(acc[mt][nf][3] * sc[mt][3] + off[mt][3], 0.f));
        *(ushort4*)(Qb + prow + wave * 32 + mt * 16 + quad * 4) = pk;
      }
    }
  } else {
    const bool isK = (wave < 2);
    floatx4 acc[4][4];
#pragma unroll
    for (int mt = 0; mt < 4; ++mt)
#pragma unroll
      for (int nf = 0; nf < 4; ++nf) acc[mt][nf] = (floatx4){0.f, 0.f, 0.f, 0.f};

#pragma unroll
    for (int ks = 0; ks < 8; ++ks) {
      short8 af[4];
#pragma unroll
      for (int mt = 0; mt < 4; ++mt)
        af[mt] = *(const short8*)&WkvP[(size_t)((((ks * 4 + wave) * 4 + mt) * 64) + lane) * 8];
#pragma unroll
      for (int nf = 0; nf < 4; ++nf) {
        const short8 bf = *(const short8*)&xT[(nf * 16 + lane16) * 264 + ks * 32 + quad * 8];
#pragma unroll
        for (int mt = 0; mt < 4; ++mt) acc[mt][nf] = MFMA(af[mt], bf, acc[mt][nf]);
      }
    }

    if (isK) {
      float sc[4][4], off[4][4];
#pragma unroll
      for (int mt = 0; mt < 4; ++mt)
#pragma unroll
        for (int r = 0; r < 4; ++r) {
          const int o = wave * 64 + mt * 16 + quad * 4 + r;
          const float s = gk[o] * rsqrtf(vk[o] + BN_EPS);
          sc[mt][r] = s;
          off[mt][r] = (bk[o] - mk[o]) * s + betak[o];
        }
#pragma unroll
      for (int nf = 0; nf < 4; ++nf) {
        const size_t prow = ((size_t)b * HW + pt * 64 + nf * 16 + lane16) * CK;
#pragma unroll
        for (int mt = 0; mt < 4; ++mt) {
          ushort4 pk;
          pk.x = f2bf(fmaxf(acc[mt][nf][0] * sc[mt][0] + off[mt][0], 0.f));
          pk.y = f2bf(fmaxf(acc[mt][nf][1] * sc[mt][1] + off[mt][1], 0.f));
          pk.z = f2bf(fmaxf(acc[mt][nf][2] * sc[mt][2] + off[mt][2], 0.f));
          pk.w = f2bf(fmaxf(acc[mt][nf][3] * sc[mt][3] + off[mt][3], 0.f));
          *(ushort4*)(Kb + prow + wave * 64 + mt * 16 + quad * 4) = pk;
        }
      }
    } else {
#pragma unroll
      for (int mt = 0; mt < 4; ++mt) {
#pragma unroll
        for (int r = 0; r < 4; ++r) {
          const int c = wave * 64 + mt * 16 + quad * 4 + r - 128;
          const float bias = bv[c];
          unsigned short* dst = Vt + ((size_t)(b * CK + c)) * HW + pt * 64;
#pragma unroll
          for (int nf = 0; nf < 4; ++nf)
            dst[nf * 16 + lane16] = f2bf(acc[mt][nf][r] + bias);
        }
      }
    }
  }
}

// ---------------------------------------------------------------------------
// Kernel 2: split-K flash attention, 32-kp tiles for small-LDS occupancy.
// LDS = 29184 B -> 4 blocks/CU (16 waves). grid 128*NKC, block 256 (4 waves).
// Wave owns 32 q rows; per iter: 32 keys staged, QK -> exp2 -> P LDS -> PV.
// ---------------------------------------------------------------------------
template<int NKC>
__global__ __launch_bounds__(256, 4) void attn_kernel6(
    const unsigned short* __restrict__ Qb, const unsigned short* __restrict__ Kb,
    const unsigned short* __restrict__ Vt, float* __restrict__ Opart,
    float* __restrict__ Ml)
{
  constexpr int ITERS = 128 / NKC;   // 32-kp tiles per chunk
  const int tid = threadIdx.x;
  const int blk = blockIdx.x;
  const int b  = blk & 3;
  const int qt = (blk >> 2) & 31;
  const int kc = blk >> 7;

  const int wave = tid >> 6;
  const int lane = tid & 63;
  const int lane16 = lane & 15;
  const int quad = lane >> 4;

  __shared__ unsigned short Kl[32 * 136];    // [kp][c], stride 136 (16B-mult)
  __shared__ unsigned short Vl[128 * 40];    // [c][kp], stride 40 (16B-mult)
  __shared__ unsigned short Pl[4][32 * 40];  // per-wave [q][kp], stride 40
  unsigned short* Pw = &Pl[wave][0];

  const int q0 = qt * 128 + wave * 32;
  short8 qf[2][4];
  {
    const unsigned short* Qs = Qb + ((size_t)b * HW + q0) * CK;
#pragma unroll
    for (int mt = 0; mt < 2; ++mt)
#pragma unroll
      for (int ks = 0; ks < 4; ++ks)
        qf[mt][ks] = *(const short8*)(Qs + (size_t)(mt * 16 + lane16) * CK + ks * 32 + quad * 8);
  }

  short8 ones;
#pragma unroll
  for (int i = 0; i < 8; ++i) ones[i] = (short)0x3F80;  // bf16 1.0

  floatx4 O[2][8];
  floatx4 Lacc[2];
#pragma unroll
  for (int mt = 0; mt < 2; ++mt) {
    Lacc[mt] = (floatx4){0.f, 0.f, 0.f, 0.f};
#pragma unroll
    for (int nf = 0; nf < 8; ++nf) O[mt][nf] = (floatx4){0.f, 0.f, 0.f, 0.f};
  }

  // staging: 8KB K (32 rows x 128c) + 8KB V (128c x 32 kp), 2 b128 each
  const int krow = tid >> 4;            // 0..15 (+16 on second pass)
  const int kcol = (tid & 15) * 8;      // shorts
  const int vrow = tid >> 1;            // 0..127 (channel)
  const int vcol = (tid & 1) * 16;      // shorts (+8 on second pass)

  const unsigned short* Kg = Kb + (size_t)b * HW * CK + (size_t)(kc * ITERS * 32) * CK;
  const unsigned short* Vg = Vt + (size_t)b * CK * HW + kc * ITERS * 32;

  short8 kr[2], vr[2];
#pragma unroll
  for (int i2 = 0; i2 < 2; ++i2)
    kr[i2] = *(const short8*)(Kg + (size_t)(krow + i2 * 16) * CK + kcol);
#pragma unroll
  for (int i2 = 0; i2 < 2; ++i2)
    vr[i2] = *(const short8*)(Vg + (size_t)vrow * HW + vcol + i2 * 8);

  for (int it = 0; it < ITERS; ++it) {
    __syncthreads();   // previous tile's LDS reads complete
#pragma unroll
    for (int i2 = 0; i2 < 2; ++i2)
      *(short8*)&Kl[(krow + i2 * 16) * 136 + kcol] = kr[i2];
#pragma unroll
    for (int i2 = 0; i2 < 2; ++i2)
      *(short8*)&Vl[vrow * 40 + vcol + i2 * 8] = vr[i2];
    __syncthreads();   // staging visible

    if (it + 1 < ITERS) {  // prefetch next tile into regs; overlaps compute
      const unsigned short* Kn = Kg + (size_t)((it + 1) * 32) * CK;
      const unsigned short* Vn = Vg + (it + 1) * 32;
#pragma unroll
      for (int i2 = 0; i2 < 2; ++i2)
        kr[i2] = *(const short8*)(Kn + (size_t)(krow + i2 * 16) * CK + kcol);
#pragma unroll
      for (int i2 = 0; i2 < 2; ++i2)
        vr[i2] = *(const short8*)(Vn + (size_t)vrow * HW + vcol + i2 * 8);
    }

    // S = Q K^T (32 q x 32 kp), P = exp2(S) immediately (scale pre-folded)
#pragma unroll
    for (int nf = 0; nf < 2; ++nf) {
      floatx4 s0 = (floatx4){0.f, 0.f, 0.f, 0.f};
      floatx4 s1 = (floatx4){0.f, 0.f, 0.f, 0.f};
#pragma unroll
      for (int ks = 0; ks < 4; ++ks) {
        const short8 kf = *(const short8*)&Kl[(nf * 16 + lane16) * 136 + ks * 32 + quad * 8];
        s0 = MFMA(qf[0][ks], kf, s0);
        s1 = MFMA(qf[1][ks], kf, s1);
      }
#pragma unroll
      for (int r = 0; r < 4; ++r) {
        Pw[(quad * 4 + r) * 40 + nf * 16 + lane16] =
            f2bf(__builtin_amdgcn_exp2f(s0[r]));
        Pw[(16 + quad * 4 + r) * 40 + nf * 16 + lane16] =
            f2bf(__builtin_amdgcn_exp2f(s1[r]));
      }
    }
    __threadfence_block();  // order P ds_writes before cross-lane ds_reads

    // O += P V ; l += P * ones   (k = 32 kp in one MFMA K-pass)
    {
      const short8 pf0 = *(const short8*)&Pw[lane16 * 40 + quad * 8];
      const short8 pf1 = *(const short8*)&Pw[(16 + lane16) * 40 + quad * 8];
      Lacc[0] = MFMA(pf0, ones, Lacc[0]);
      Lacc[1] = MFMA(pf1, ones, Lacc[1]);
#pragma unroll
      for (int nf = 0; nf < 8; ++nf) {
        const short8 vf = *(const short8*)&Vl[(nf * 16 + lane16) * 40 + quad * 8];
        O[0][nf] = MFMA(pf0, vf, O[0][nf]);
        O[1][nf] = MFMA(pf1, vf, O[1][nf]);
      }
    }
  }

  const int chunk = (b * 32 + qt) * NKC + kc;
  float* Op = Opart + (size_t)chunk * (128 * 128);
#pragma unroll
  for (int mt = 0; mt < 2; ++mt)
#pragma unroll
    for (int nf = 0; nf < 8; ++nf)
#pragma unroll
      for (int r = 0; r < 4; ++r)
        Op[(size_t)(wave * 32 + mt * 16 + quad * 4 + r) * 128 + nf * 16 + lane16] = O[mt][nf][r];
  if (lane16 == 0) {
    float* Mp = Ml + (size_t)chunk * 128 + wave * 32;
#pragma unroll
    for (int mt = 0; mt < 2; ++mt)
#pragma unroll
      for (int r = 0; r < 4; ++r)
        Mp[mt * 16 + quad * 4 + r] = Lacc[mt][r];
  }
}

// ---------------------------------------------------------------------------
// Kernel 3: fused combine + out-projection. (unchanged, round 5)
// ---------------------------------------------------------------------------
template<int NKC>
__global__ __launch_bounds__(256) void outproj_kernel(
    const float* __restrict__ Opart, const float* __restrict__ Ml,
    const unsigned short* __restrict__ WoP, const float* __restrict__ bo,
    float* __restrict__ out)
{
  const int tid = threadIdx.x;
  const int pt = blockIdx.x;
  const int b  = blockIdx.y;
  const int qt = pt >> 3;
  const int q0 = (pt & 7) * 16;
  const int chunk0 = (b * 32 + qt) * NKC;

  __shared__ unsigned short Ctile[16 * 136];

  {
    const int row = tid >> 4;
    const int c8  = (tid & 15) * 8;
    float L = 0.f;
#pragma unroll
    for (int k = 0; k < NKC; ++k) L += Ml[(size_t)(chunk0 + k) * 128 + q0 + row];
    float acc[8];
#pragma unroll
    for (int i = 0; i < 8; ++i) acc[i] = 0.f;
#pragma unroll
    for (int k = 0; k < NKC; ++k) {
      const float* Op = Opart + (size_t)(chunk0 + k) * 16384 + (size_t)(q0 + row) * 128 + c8;
      const float4 v0 = *(const float4*)(Op);
      const float4 v1 = *(const float4*)(Op + 4);
      acc[0] += v0.x; acc[1] += v0.y; acc[2] += v0.z; acc[3] += v0.w;
      acc[4] += v1.x; acc[5] += v1.y; acc[6] += v1.z; acc[7] += v1.w;
    }
    const float inv = 1.f / L;
#pragma unroll
    for (int i = 0; i < 8; ++i) acc[i] *= inv;
    *(short8*)&Ctile[row * 136 + c8] = pack8(acc);
  }
  __syncthreads();

  const int wave = tid >> 6;
  const int lane = tid & 63;
  const int lane16 = lane & 15;
  const int quad = lane >> 4;

  floatx4 acc[4];
#pragma unroll
  for (int mt = 0; mt < 4; ++mt) acc[mt] = (floatx4){0.f, 0.f, 0.f, 0.f};

#pragma unroll
  for (int ks = 0; ks < 4; ++ks) {
    const short8 bf = *(const short8*)&Ctile[lane16 * 136 + ks * 32 + quad * 8];
#pragma unroll
    for (int mt = 0; mt < 4; ++mt) {
      const short8 af = *(const short8*)&WoP[(size_t)((((ks * 4 + wave) * 4 + mt) * 64) + lane) * 8];
      acc[mt] = MFMA(af, bf, acc[mt]);
    }
  }

#pragma unroll
  for (int mt = 0; mt < 4; ++mt) {
#pragma unroll
    for (int r = 0; r < 4; ++r) {
      const int o = wave * 64 + mt * 16 + quad * 4 + r;
      float* dst = out + ((size_t)b * COUT + o) * HW + qt * 128 + q0;
      dst[lane16] = acc[mt][r] + bo[o];
    }
  }
}

extern "C" void kernel_launch(void* const* d_in, const int* in_sizes, int n_in,
                              void* d_out, int out_size, void* d_ws, size_t ws_size,
                              hipStream_t stream)
{
  (void)in_sizes; (void)n_in; (void)out_size;
  const float* x_enc = (const float*)d_in[0];
  const float* x_dec = (const float*)d_in[1];
  const float* wk    = (const float*)d_in[2];
  const float* bk    = (const float*)d_in[3];
  const float* gk    = (const float*)d_in[4];
  const float* betak = (const float*)d_in[5];
  const float* mk    = (const float*)d_in[6];
  const float* vk    = (const float*)d_in[7];
  const float* wq    = (const float*)d_in[8];
  const float* bq    = (const float*)d_in[9];
  const float* gq    = (const float*)d_in[10];
  const float* betaq = (const float*)d_in[11];
  const float* mq    = (const float*)d_in[12];
  const float* vq    = (const float*)d_in[13];
  const float* wv    = (const float*)d_in[14];
  const float* bv    = (const float*)d_in[15];
  const float* wo    = (const float*)d_in[16];
  const float* bo    = (const float*)d_in[17];
  float* out = (float*)d_out;

  const size_t qkv = (size_t)NB * HW * CK;  // elems per bf16 tensor
  unsigned short* WqP  = (unsigned short*)d_ws;      // 32768 shorts
  unsigned short* WkvP = WqP + 32768;                // 65536 shorts
  unsigned short* WoP  = WkvP + 65536;               // 32768 shorts
  unsigned short* Qb   = WoP + 32768;
  unsigned short* Kb   = Qb + qkv;
  unsigned short* Vt   = Kb + qkv;
  float* Opart = (float*)(Vt + qkv);
  const size_t fixed_bytes = 131072 * 2 + 3 * qkv * 2;

  prep_kernel<<<dim3(64), 256, 0, stream>>>(wq, wk, wv, wo, WqP, WkvP, WoP);
  proj_kernel<<<dim3(64, 4, 2), 256, 0, stream>>>(
      x_enc, x_dec, WqP, WkvP,
      bq, gq, betaq, mq, vq, bk, gk, betak, mk, vk, bv, Qb, Kb, Vt);

  auto need = [&](int nkc) {
    return fixed_bytes + (size_t)128 * nkc * (16384 + 128) * sizeof(float);
  };
  if (ws_size >= need(8)) {
    float* Ml = Opart + (size_t)128 * 8 * 16384;
    attn_kernel6<8><<<dim3(1024), 256, 0, stream>>>(Qb, Kb, Vt, Opart, Ml);
    outproj_kernel<8><<<dim3(256, 4), 256, 0, stream>>>(Opart, Ml, WoP, bo, out);
  } else if (ws_size >= need(4)) {
    float* Ml = Opart + (size_t)128 * 4 * 16384;
    attn_kernel6<4><<<dim3(512), 256, 0, stream>>>(Qb, Kb, Vt, Opart, Ml);
    outproj_kernel<4><<<dim3(256, 4), 256, 0, stream>>>(Opart, Ml, WoP, bo, out);
  } else if (ws_size >= need(2)) {
    float* Ml = Opart + (size_t)128 * 2 * 16384;
    attn_kernel6<2><<<dim3(256), 256, 0, stream>>>(Qb, Kb, Vt, Opart, Ml);
    outproj_kernel<2><<<dim3(256, 4), 256, 0, stream>>>(Opart, Ml, WoP, bo, out);
  } else {
    float* Ml = Opart + (size_t)128 * 1 * 16384;
    attn_kernel6<1><<<dim3(128), 256, 0, stream>>>(Qb, Kb, Vt, Opart, Ml);
    outproj_kernel<1><<<dim3(256, 4), 256, 0, stream>>>(Opart, Ml, WoP, bo, out);
  }
}

// Round 7
// 191.333 us; speedup vs baseline: 1.0782x; 1.0782x over previous
//
#include <hip/hip_runtime.h>

typedef __attribute__((ext_vector_type(8))) short short8;
typedef __attribute__((ext_vector_type(4))) float floatx4;

#define HW 4096
#define CIN 256
#define CK 128
#define COUT 256
#define NB 4
#define BN_EPS 1e-5f
// (1/sqrt(128)) * log2(e), folded into Q at projection time -> P = exp2(S)
#define SC2 0.12751744526f

#define MFMA(a, b, c) __builtin_amdgcn_mfma_f32_16x16x32_bf16((a), (b), (c), 0, 0, 0)

__device__ __forceinline__ unsigned short f2bf(float f) {
  union { float f; unsigned u; } v; v.f = f;
  unsigned r = v.u + 0x7fffu + ((v.u >> 16) & 1u);  // RNE
  return (unsigned short)(r >> 16);
}

__device__ __forceinline__ short8 pack8(const float* p) {
  short8 r;
#pragma unroll
  for (int i = 0; i < 8; ++i) r[i] = (short)f2bf(p[i]);
  return r;
}

// ---------------------------------------------------------------------------
// Kernel 0: pre-pack weights as bf16 in MFMA A-fragment order (coalesced
// 16B/lane loads in proj/outproj). Layouts as in round 5.
// ---------------------------------------------------------------------------
__global__ __launch_bounds__(256) void prep_kernel(
    const float* __restrict__ wq, const float* __restrict__ wk,
    const float* __restrict__ wv, const float* __restrict__ wo,
    unsigned short* __restrict__ WqP, unsigned short* __restrict__ WkvP,
    unsigned short* __restrict__ WoP)
{
  const int t = blockIdx.x * 256 + threadIdx.x;  // 0..16383
  float tmp[8];
  if (t < 4096) {
    const int lane = t & 63, mt = (t >> 6) & 1, wave = (t >> 7) & 3, ks = t >> 9;
    const int lane16 = lane & 15, quad = lane >> 4;
    const int o = wave * 32 + mt * 16 + lane16;
    const float* src = wq + (size_t)o * CIN + ks * 32 + quad * 8;
    *(float4*)tmp = *(const float4*)src;
    *(float4*)(tmp + 4) = *(const float4*)(src + 4);
    *(short8*)&WqP[(size_t)t * 8] = pack8(tmp);
  } else if (t < 12288) {
    const int u = t - 4096;
    const int lane = u & 63, mt = (u >> 6) & 3, wave = (u >> 8) & 3, ks = u >> 10;
    const int lane16 = lane & 15, quad = lane >> 4;
    const int o = wave * 64 + mt * 16 + lane16;
    const float* row = (o < 128) ? wk + (size_t)o * CIN : wv + (size_t)(o - 128) * CIN;
    const float* src = row + ks * 32 + quad * 8;
    *(float4*)tmp = *(const float4*)src;
    *(float4*)(tmp + 4) = *(const float4*)(src + 4);
    *(short8*)&WkvP[(size_t)u * 8] = pack8(tmp);
  } else {
    const int u = t - 12288;
    const int lane = u & 63, mt = (u >> 6) & 3, wave = (u >> 8) & 3, ks = u >> 10;
    const int lane16 = lane & 15, quad = lane >> 4;
    const int o = wave * 64 + mt * 16 + lane16;
    const float* src = wo + (size_t)o * CK + ks * 32 + quad * 8;
    *(float4*)tmp = *(const float4*)src;
    *(float4*)(tmp + 4) = *(const float4*)(src + 4);
    *(short8*)&WoP[(size_t)u * 8] = pack8(tmp);
  }
}

// ---------------------------------------------------------------------------
// Kernel 1: projections. grid (64, 4, 2), block 256. (unchanged, round 5)
// ---------------------------------------------------------------------------
__global__ __launch_bounds__(256) void proj_kernel(
    const float* __restrict__ x_enc, const float* __restrict__ x_dec,
    const unsigned short* __restrict__ WqP, const unsigned short* __restrict__ WkvP,
    const float* __restrict__ bq, const float* __restrict__ gq,
    const float* __restrict__ betaq, const float* __restrict__ mq,
    const float* __restrict__ vq,
    const float* __restrict__ bk, const float* __restrict__ gk,
    const float* __restrict__ betak, const float* __restrict__ mk,
    const float* __restrict__ vk, const float* __restrict__ bv,
    unsigned short* __restrict__ Qb, unsigned short* __restrict__ Kb,
    unsigned short* __restrict__ Vt)
{
  const int tid = threadIdx.x;
  const int pt = blockIdx.x;
  const int b  = blockIdx.y;
  const int pj = blockIdx.z;

  const float* X = (pj == 0) ? x_dec : x_enc;

  __shared__ float xF[64 * 68];
  __shared__ unsigned short xT[64 * 264];

  const float* Xs = X + (size_t)b * CIN * HW + (size_t)pt * 64;
#pragma unroll
  for (int qtr = 0; qtr < 4; ++qtr) {
    if (qtr) __syncthreads();
    {
      const int c = tid >> 2;
      const int p0 = (tid & 3) * 16;
      const float* src = Xs + (size_t)(qtr * 64 + c) * HW + p0;
#pragma unroll
      for (int j = 0; j < 4; ++j)
        *(float4*)&xF[c * 68 + p0 + j * 4] = *(const float4*)(src + j * 4);
    }
    __syncthreads();
    {
      const int p = tid & 63;
      const int cb = tid >> 6;
#pragma unroll
      for (int jj = 0; jj < 2; ++jj) {
        const int c0 = (jj * 4 + cb) * 8;
        float t[8];
#pragma unroll
        for (int u = 0; u < 8; ++u) t[u] = xF[(c0 + u) * 68 + p];
        *(short8*)&xT[p * 264 + qtr * 64 + c0] = pack8(t);
      }
    }
  }
  __syncthreads();

  const int wave = tid >> 6;
  const int lane = tid & 63;
  const int lane16 = lane & 15;
  const int quad = lane >> 4;

  if (pj == 0) {
    floatx4 acc[2][4];
#pragma unroll
    for (int mt = 0; mt < 2; ++mt)
#pragma unroll
      for (int nf = 0; nf < 4; ++nf) acc[mt][nf] = (floatx4){0.f, 0.f, 0.f, 0.f};

#pragma unroll
    for (int ks = 0; ks < 8; ++ks) {
      short8 af[2];
#pragma unroll
      for (int mt = 0; mt < 2; ++mt)
        af[mt] = *(const short8*)&WqP[(size_t)((((ks * 4 + wave) * 2 + mt) * 64) + lane) * 8];
#pragma unroll
      for (int nf = 0; nf < 4; ++nf) {
        const short8 bf = *(const short8*)&xT[(nf * 16 + lane16) * 264 + ks * 32 + quad * 8];
#pragma unroll
        for (int mt = 0; mt < 2; ++mt) acc[mt][nf] = MFMA(af[mt], bf, acc[mt][nf]);
      }
    }

    float sc[2][4], off[2][4];
#pragma unroll
    for (int mt = 0; mt < 2; ++mt)
#pragma unroll
      for (int r = 0; r < 4; ++r) {
        const int o = wave * 32 + mt * 16 + quad * 4 + r;
        const float s = gq[o] * rsqrtf(vq[o] + BN_EPS) * SC2;
        sc[mt][r] = s;
        off[mt][r] = (bq[o] - mq[o]) * s + betaq[o] * SC2;
      }
#pragma unroll
    for (int nf = 0; nf < 4; ++nf) {
      const size_t prow = ((size_t)b * HW + pt * 64 + nf * 16 + lane16) * CK;
#pragma unroll
      for (int mt = 0; mt < 2; ++mt) {
        ushort4 pk;
        pk.x = f2bf(fmaxf(acc[mt][nf][0] * sc[mt][0] + off[mt][0], 0.f));
        pk.y = f2bf(fmaxf(acc[mt][nf][1] * sc[mt][1] + off[mt][1], 0.f));
        pk.z = f2bf(fmaxf(acc[mt][nf][2] * sc[mt][2] + off[mt][2], 0.f));
        pk.w = f2bf(fmaxf(acc[mt][nf][3] * sc[mt][3] + off[mt][3], 0.f));
        *(ushort4*)(Qb + prow + wave * 32 + mt * 16 + quad * 4) = pk;
      }
    }
  } else {
    const bool isK = (wave < 2);
    floatx4 acc[4][4];
#pragma unroll
    for (int mt = 0; mt < 4; ++mt)
#pragma unroll
      for (int nf = 0; nf < 4; ++nf) acc[mt][nf] = (floatx4){0.f, 0.f, 0.f, 0.f};

#pragma unroll
    for (int ks = 0; ks < 8; ++ks) {
      short8 af[4];
#pragma unroll
      for (int mt = 0; mt < 4; ++mt)
        af[mt] = *(const short8*)&WkvP[(size_t)((((ks * 4 + wave) * 4 + mt) * 64) + lane) * 8];
#pragma unroll
      for (int nf = 0; nf < 4; ++nf) {
        const short8 bf = *(const short8*)&xT[(nf * 16 + lane16) * 264 + ks * 32 + quad * 8];
#pragma unroll
        for (int mt = 0; mt < 4; ++mt) acc[mt][nf] = MFMA(af[mt], bf, acc[mt][nf]);
      }
    }

    if (isK) {
      float sc[4][4], off[4][4];
#pragma unroll
      for (int mt = 0; mt < 4; ++mt)
#pragma unroll
        for (int r = 0; r < 4; ++r) {
          const int o = wave * 64 + mt * 16 + quad * 4 + r;
          const float s = gk[o] * rsqrtf(vk[o] + BN_EPS);
          sc[mt][r] = s;
          off[mt][r] = (bk[o] - mk[o]) * s + betak[o];
        }
#pragma unroll
      for (int nf = 0; nf < 4; ++nf) {
        const size_t prow = ((size_t)b * HW + pt * 64 + nf * 16 + lane16) * CK;
#pragma unroll
        for (int mt = 0; mt < 4; ++mt) {
          ushort4 pk;
          pk.x = f2bf(fmaxf(acc[mt][nf][0] * sc[mt][0] + off[mt][0], 0.f));
          pk.y = f2bf(fmaxf(acc[mt][nf][1] * sc[mt][1] + off[mt][1], 0.f));
          pk.z = f2bf(fmaxf(acc[mt][nf][2] * sc[mt][2] + off[mt][2], 0.f));
          pk.w = f2bf(fmaxf(acc[mt][nf][3] * sc[mt][3] + off[mt][3], 0.f));
          *(ushort4*)(Kb + prow + wave * 64 + mt * 16 + quad * 4) = pk;
        }
      }
    } else {
#pragma unroll
      for (int mt = 0; mt < 4; ++mt) {
#pragma unroll
        for (int r = 0; r < 4; ++r) {
          const int c = wave * 64 + mt * 16 + quad * 4 + r - 128;
          const float bias = bv[c];
          unsigned short* dst = Vt + ((size_t)(b * CK + c)) * HW + pt * 64;
#pragma unroll
          for (int nf = 0; nf < 4; ++nf)
            dst[nf * 16 + lane16] = f2bf(acc[mt][nf][r] + bias);
        }
      }
    }
  }
}

// ---------------------------------------------------------------------------
// Kernel 2: split-K flash attention, 64 q per wave (256 q per block).
// 64-kp staged tiles (round-5 L2-proven), P handled in two 32-kp halves to
// keep LDS at 56.3KB (<64KB WG limit, 2 blocks/CU like round 5).
// grid 64*NKC (b=blk&3, qt=(blk>>2)&15, kc=blk>>6), block 256 (4 waves).
// ---------------------------------------------------------------------------
template<int NKC>
__global__ __launch_bounds__(256, 2) void attn_kernel7(
    const unsigned short* __restrict__ Qb, const unsigned short* __restrict__ Kb,
    const unsigned short* __restrict__ Vt, float* __restrict__ Opart,
    float* __restrict__ Ml)
{
  constexpr int ITERS = 64 / NKC;
  const int tid = threadIdx.x;
  const int blk = blockIdx.x;
  const int b  = blk & 3;
  const int qt = (blk >> 2) & 15;
  const int kc = blk >> 6;

  const int wave = tid >> 6;
  const int lane = tid & 63;
  const int lane16 = lane & 15;
  const int quad = lane >> 4;

  __shared__ unsigned short Kl[64 * 136];    // [kp][c], stride 136
  __shared__ unsigned short Vl[128 * 72];    // [c][kp], stride 72
  __shared__ unsigned short Pl[4][64 * 40];  // per-wave [q64][kp32], stride 40
  unsigned short* Pw = &Pl[wave][0];

  const int q0 = qt * 256 + wave * 64;
  short8 qf[4][4];
  {
    const unsigned short* Qs = Qb + ((size_t)b * HW + q0) * CK;
#pragma unroll
    for (int mt = 0; mt < 4; ++mt)
#pragma unroll
      for (int ks = 0; ks < 4; ++ks)
        qf[mt][ks] = *(const short8*)(Qs + (size_t)(mt * 16 + lane16) * CK + ks * 32 + quad * 8);
  }

  short8 ones;
#pragma unroll
  for (int i = 0; i < 8; ++i) ones[i] = (short)0x3F80;  // bf16 1.0

  floatx4 O[4][8];
  floatx4 Lacc[4];
#pragma unroll
  for (int mt = 0; mt < 4; ++mt) {
    Lacc[mt] = (floatx4){0.f, 0.f, 0.f, 0.f};
#pragma unroll
    for (int nf = 0; nf < 8; ++nf) O[mt][nf] = (floatx4){0.f, 0.f, 0.f, 0.f};
  }

  // staging: 16KB K (64 rows x 128c) + 16KB V (128c x 64 kp)
  const int krow = tid >> 4;           // 0..15
  const int kcol = (tid & 15) * 8;     // shorts
  const int vrow = tid >> 1;           // 0..127 (channel)
  const int vcol = (tid & 1) * 32;     // shorts

  const unsigned short* Kg = Kb + (size_t)b * HW * CK + (size_t)(kc * ITERS * 64) * CK;
  const unsigned short* Vg = Vt + (size_t)b * CK * HW + kc * ITERS * 64;

  short8 kr[4], vr[4];
#pragma unroll
  for (int i2 = 0; i2 < 4; ++i2)
    kr[i2] = *(const short8*)(Kg + (size_t)(krow + i2 * 16) * CK + kcol);
#pragma unroll
  for (int i2 = 0; i2 < 4; ++i2)
    vr[i2] = *(const short8*)(Vg + (size_t)vrow * HW + vcol + i2 * 8);

  for (int it = 0; it < ITERS; ++it) {
    __syncthreads();   // previous tile's LDS reads complete
#pragma unroll
    for (int i2 = 0; i2 < 4; ++i2)
      *(short8*)&Kl[(krow + i2 * 16) * 136 + kcol] = kr[i2];
#pragma unroll
    for (int i2 = 0; i2 < 4; ++i2)
      *(short8*)&Vl[vrow * 72 + vcol + i2 * 8] = vr[i2];
    __syncthreads();   // staging visible

    if (it + 1 < ITERS) {  // prefetch next tile into regs; overlaps compute
      const unsigned short* Kn = Kg + (size_t)((it + 1) * 64) * CK;
      const unsigned short* Vn = Vg + (it + 1) * 64;
#pragma unroll
      for (int i2 = 0; i2 < 4; ++i2)
        kr[i2] = *(const short8*)(Kn + (size_t)(krow + i2 * 16) * CK + kcol);
#pragma unroll
      for (int i2 = 0; i2 < 4; ++i2)
        vr[i2] = *(const short8*)(Vn + (size_t)vrow * HW + vcol + i2 * 8);
    }

    // process the 64-kp tile in two 32-kp halves (P buffer is 64q x 32kp)
#pragma unroll
    for (int h = 0; h < 2; ++h) {
      // S = Q K^T (64 q x 32 kp), P = exp2(S) into per-wave LDS
#pragma unroll
      for (int nfl = 0; nfl < 2; ++nfl) {
        floatx4 s[4];
#pragma unroll
        for (int mt = 0; mt < 4; ++mt) s[mt] = (floatx4){0.f, 0.f, 0.f, 0.f};
#pragma unroll
        for (int ks = 0; ks < 4; ++ks) {
          const short8 kf = *(const short8*)&Kl[(h * 32 + nfl * 16 + lane16) * 136 + ks * 32 + quad * 8];
#pragma unroll
          for (int mt = 0; mt < 4; ++mt) s[mt] = MFMA(qf[mt][ks], kf, s[mt]);
        }
#pragma unroll
        for (int mt = 0; mt < 4; ++mt)
#pragma unroll
          for (int r = 0; r < 4; ++r)
            Pw[(mt * 16 + quad * 4 + r) * 40 + nfl * 16 + lane16] =
                f2bf(__builtin_amdgcn_exp2f(s[mt][r]));
      }
      __threadfence_block();  // order P ds_writes before cross-lane ds_reads

      // O += P V ; l += P * ones  (one k=32 MFMA pass per half)
      short8 pf[4];
#pragma unroll
      for (int mt = 0; mt < 4; ++mt) {
        pf[mt] = *(const short8*)&Pw[(mt * 16 + lane16) * 40 + quad * 8];
        Lacc[mt] = MFMA(pf[mt], ones, Lacc[mt]);
      }
#pragma unroll
      for (int nf = 0; nf < 8; ++nf) {
        const short8 vf = *(const short8*)&Vl[(nf * 16 + lane16) * 72 + h * 32 + quad * 8];
#pragma unroll
        for (int mt = 0; mt < 4; ++mt) O[mt][nf] = MFMA(pf[mt], vf, O[mt][nf]);
      }
      __threadfence_block();  // half h reads done before half h+1 overwrites
    }
  }

  const int chunk = (b * 16 + qt) * NKC + kc;
  float* Op = Opart + (size_t)chunk * (256 * 128);
#pragma unroll
  for (int mt = 0; mt < 4; ++mt)
#pragma unroll
    for (int nf = 0; nf < 8; ++nf)
#pragma unroll
      for (int r = 0; r < 4; ++r)
        Op[(size_t)(wave * 64 + mt * 16 + quad * 4 + r) * 128 + nf * 16 + lane16] = O[mt][nf][r];
  if (lane16 == 0) {
    float* Mp = Ml + (size_t)chunk * 256 + wave * 64;
#pragma unroll
    for (int mt = 0; mt < 4; ++mt)
#pragma unroll
      for (int r = 0; r < 4; ++r)
        Mp[mt * 16 + quad * 4 + r] = Lacc[mt][r];
  }
}

// ---------------------------------------------------------------------------
// Kernel 3: fused combine + out-projection. grid (256 p-tiles of 16, 4 batch).
// Chunk layout updated for 256-q attn tiles.
// ---------------------------------------------------------------------------
template<int NKC>
__global__ __launch_bounds__(256) void outproj_kernel(
    const float* __restrict__ Opart, const float* __restrict__ Ml,
    const unsigned short* __restrict__ WoP, const float* __restrict__ bo,
    float* __restrict__ out)
{
  const int tid = threadIdx.x;
  const int pt = blockIdx.x;          // 16-position tile (0..255)
  const int b  = blockIdx.y;
  const int qt  = pt >> 4;            // 256-q attn tile (0..15)
  const int qin = (pt & 15) * 16;     // offset within tile
  const int chunk0 = (b * 16 + qt) * NKC;

  __shared__ unsigned short Ctile[16 * 136];

  {
    const int row = tid >> 4;
    const int c8  = (tid & 15) * 8;
    float L = 0.f;
#pragma unroll
    for (int k = 0; k < NKC; ++k) L += Ml[(size_t)(chunk0 + k) * 256 + qin + row];
    float acc[8];
#pragma unroll
    for (int i = 0; i < 8; ++i) acc[i] = 0.f;
#pragma unroll
    for (int k = 0; k < NKC; ++k) {
      const float* Op = Opart + (size_t)(chunk0 + k) * 32768 + (size_t)(qin + row) * 128 + c8;
      const float4 v0 = *(const float4*)(Op);
      const float4 v1 = *(const float4*)(Op + 4);
      acc[0] += v0.x; acc[1] += v0.y; acc[2] += v0.z; acc[3] += v0.w;
      acc[4] += v1.x; acc[5] += v1.y; acc[6] += v1.z; acc[7] += v1.w;
    }
    const float inv = 1.f / L;
#pragma unroll
    for (int i = 0; i < 8; ++i) acc[i] *= inv;
    *(short8*)&Ctile[row * 136 + c8] = pack8(acc);
  }
  __syncthreads();

  const int wave = tid >> 6;
  const int lane = tid & 63;
  const int lane16 = lane & 15;
  const int quad = lane >> 4;

  floatx4 acc[4];
#pragma unroll
  for (int mt = 0; mt < 4; ++mt) acc[mt] = (floatx4){0.f, 0.f, 0.f, 0.f};

#pragma unroll
  for (int ks = 0; ks < 4; ++ks) {
    const short8 bf = *(const short8*)&Ctile[lane16 * 136 + ks * 32 + quad * 8];
#pragma unroll
    for (int mt = 0; mt < 4; ++mt) {
      const short8 af = *(const short8*)&WoP[(size_t)((((ks * 4 + wave) * 4 + mt) * 64) + lane) * 8];
      acc[mt] = MFMA(af, bf, acc[mt]);
    }
  }

#pragma unroll
  for (int mt = 0; mt < 4; ++mt) {
#pragma unroll
    for (int r = 0; r < 4; ++r) {
      const int o = wave * 64 + mt * 16 + quad * 4 + r;
      float* dst = out + ((size_t)b * COUT + o) * HW + qt * 256 + qin;
      dst[lane16] = acc[mt][r] + bo[o];
    }
  }
}

extern "C" void kernel_launch(void* const* d_in, const int* in_sizes, int n_in,
                              void* d_out, int out_size, void* d_ws, size_t ws_size,
                              hipStream_t stream)
{
  (void)in_sizes; (void)n_in; (void)out_size;
  const float* x_enc = (const float*)d_in[0];
  const float* x_dec = (const float*)d_in[1];
  const float* wk    = (const float*)d_in[2];
  const float* bk    = (const float*)d_in[3];
  const float* gk    = (const float*)d_in[4];
  const float* betak = (const float*)d_in[5];
  const float* mk    = (const float*)d_in[6];
  const float* vk    = (const float*)d_in[7];
  const float* wq    = (const float*)d_in[8];
  const float* bq    = (const float*)d_in[9];
  const float* gq    = (const float*)d_in[10];
  const float* betaq = (const float*)d_in[11];
  const float* mq    = (const float*)d_in[12];
  const float* vq    = (const float*)d_in[13];
  const float* wv    = (const float*)d_in[14];
  const float* bv    = (const float*)d_in[15];
  const float* wo    = (const float*)d_in[16];
  const float* bo    = (const float*)d_in[17];
  float* out = (float*)d_out;

  const size_t qkv = (size_t)NB * HW * CK;  // elems per bf16 tensor
  unsigned short* WqP  = (unsigned short*)d_ws;      // 32768 shorts
  unsigned short* WkvP = WqP + 32768;                // 65536 shorts
  unsigned short* WoP  = WkvP + 65536;               // 32768 shorts
  unsigned short* Qb   = WoP + 32768;
  unsigned short* Kb   = Qb + qkv;
  unsigned short* Vt   = Kb + qkv;
  float* Opart = (float*)(Vt + qkv);
  const size_t fixed_bytes = 131072 * 2 + 3 * qkv * 2;

  prep_kernel<<<dim3(64), 256, 0, stream>>>(wq, wk, wv, wo, WqP, WkvP, WoP);
  proj_kernel<<<dim3(64, 4, 2), 256, 0, stream>>>(
      x_enc, x_dec, WqP, WkvP,
      bq, gq, betaq, mq, vq, bk, gk, betak, mk, vk, bv, Qb, Kb, Vt);

  auto need = [&](int nkc) {
    return fixed_bytes + (size_t)64 * nkc * (32768 + 256) * sizeof(float);
  };
  if (ws_size >= need(8)) {
    float* Ml = Opart + (size_t)64 * 8 * 32768;
    attn_kernel7<8><<<dim3(512), 256, 0, stream>>>(Qb, Kb, Vt, Opart, Ml);
    outproj_kernel<8><<<dim3(256, 4), 256, 0, stream>>>(Opart, Ml, WoP, bo, out);
  } else if (ws_size >= need(4)) {
    float* Ml = Opart + (size_t)64 * 4 * 32768;
    attn_kernel7<4><<<dim3(256), 256, 0, stream>>>(Qb, Kb, Vt, Opart, Ml);
    outproj_kernel<4><<<dim3(256, 4), 256, 0, stream>>>(Opart, Ml, WoP, bo, out);
  } else if (ws_size >= need(2)) {
    float* Ml = Opart + (size_t)64 * 2 * 32768;
    attn_kernel7<2><<<dim3(128), 256, 0, stream>>>(Qb, Kb, Vt, Opart, Ml);
    outproj_kernel<2><<<dim3(256, 4), 256, 0, stream>>>(Opart, Ml, WoP, bo, out);
  } else {
    float* Ml = Opart + (size_t)64 * 1 * 32768;
    attn_kernel7<1><<<dim3(64), 256, 0, stream>>>(Qb, Kb, Vt, Opart, Ml);
    outproj_kernel<1><<<dim3(256, 4), 256, 0, stream>>>(Opart, Ml, WoP, bo, out);
  }
}

// Round 8
// 174.216 us; speedup vs baseline: 1.1841x; 1.0982x over previous
//
#include <hip/hip_runtime.h>

typedef __attribute__((ext_vector_type(8))) short short8;
typedef __attribute__((ext_vector_type(4))) float floatx4;

#define HW 4096
#define CIN 256
#define CK 128
#define COUT 256
#define NB 4
#define BN_EPS 1e-5f
// (1/sqrt(128)) * log2(e), folded into Q at projection time -> P = exp2(S)
#define SC2 0.12751744526f

#define MFMA(a, b, c) __builtin_amdgcn_mfma_f32_16x16x32_bf16((a), (b), (c), 0, 0, 0)

__device__ __forceinline__ unsigned short f2bf(float f) {
  union { float f; unsigned u; } v; v.f = f;
  unsigned r = v.u + 0x7fffu + ((v.u >> 16) & 1u);  // RNE
  return (unsigned short)(r >> 16);
}

__device__ __forceinline__ float bf2f(unsigned short u) {
  union { unsigned u; float f; } v; v.u = ((unsigned)u) << 16;
  return v.f;
}

__device__ __forceinline__ short8 pack8(const float* p) {
  short8 r;
#pragma unroll
  for (int i = 0; i < 8; ++i) r[i] = (short)f2bf(p[i]);
  return r;
}

// ---------------------------------------------------------------------------
// Kernel 0: pre-pack weights as bf16 in MFMA A-fragment order (coalesced
// 16B/lane loads in proj/outproj). Layouts as in round 5.
// ---------------------------------------------------------------------------
__global__ __launch_bounds__(256) void prep_kernel(
    const float* __restrict__ wq, const float* __restrict__ wk,
    const float* __restrict__ wv, const float* __restrict__ wo,
    unsigned short* __restrict__ WqP, unsigned short* __restrict__ WkvP,
    unsigned short* __restrict__ WoP)
{
  const int t = blockIdx.x * 256 + threadIdx.x;  // 0..16383
  float tmp[8];
  if (t < 4096) {
    const int lane = t & 63, mt = (t >> 6) & 1, wave = (t >> 7) & 3, ks = t >> 9;
    const int lane16 = lane & 15, quad = lane >> 4;
    const int o = wave * 32 + mt * 16 + lane16;
    const float* src = wq + (size_t)o * CIN + ks * 32 + quad * 8;
    *(float4*)tmp = *(const float4*)src;
    *(float4*)(tmp + 4) = *(const float4*)(src + 4);
    *(short8*)&WqP[(size_t)t * 8] = pack8(tmp);
  } else if (t < 12288) {
    const int u = t - 4096;
    const int lane = u & 63, mt = (u >> 6) & 3, wave = (u >> 8) & 3, ks = u >> 10;
    const int lane16 = lane & 15, quad = lane >> 4;
    const int o = wave * 64 + mt * 16 + lane16;
    const float* row = (o < 128) ? wk + (size_t)o * CIN : wv + (size_t)(o - 128) * CIN;
    const float* src = row + ks * 32 + quad * 8;
    *(float4*)tmp = *(const float4*)src;
    *(float4*)(tmp + 4) = *(const float4*)(src + 4);
    *(short8*)&WkvP[(size_t)u * 8] = pack8(tmp);
  } else {
    const int u = t - 12288;
    const int lane = u & 63, mt = (u >> 6) & 3, wave = (u >> 8) & 3, ks = u >> 10;
    const int lane16 = lane & 15, quad = lane >> 4;
    const int o = wave * 64 + mt * 16 + lane16;
    const float* src = wo + (size_t)o * CK + ks * 32 + quad * 8;
    *(float4*)tmp = *(const float4*)src;
    *(float4*)(tmp + 4) = *(const float4*)(src + 4);
    *(short8*)&WoP[(size_t)u * 8] = pack8(tmp);
  }
}

// ---------------------------------------------------------------------------
// Kernel 1: projections. grid (64, 4, 2), block 256. (unchanged, round 5)
// ---------------------------------------------------------------------------
__global__ __launch_bounds__(256) void proj_kernel(
    const float* __restrict__ x_enc, const float* __restrict__ x_dec,
    const unsigned short* __restrict__ WqP, const unsigned short* __restrict__ WkvP,
    const float* __restrict__ bq, const float* __restrict__ gq,
    const float* __restrict__ betaq, const float* __restrict__ mq,
    const float* __restrict__ vq,
    const float* __restrict__ bk, const float* __restrict__ gk,
    const float* __restrict__ betak, const float* __restrict__ mk,
    const float* __restrict__ vk, const float* __restrict__ bv,
    unsigned short* __restrict__ Qb, unsigned short* __restrict__ Kb,
    unsigned short* __restrict__ Vt)
{
  const int tid = threadIdx.x;
  const int pt = blockIdx.x;
  const int b  = blockIdx.y;
  const int pj = blockIdx.z;

  const float* X = (pj == 0) ? x_dec : x_enc;

  __shared__ float xF[64 * 68];
  __shared__ unsigned short xT[64 * 264];

  const float* Xs = X + (size_t)b * CIN * HW + (size_t)pt * 64;
#pragma unroll
  for (int qtr = 0; qtr < 4; ++qtr) {
    if (qtr) __syncthreads();
    {
      const int c = tid >> 2;
      const int p0 = (tid & 3) * 16;
      const float* src = Xs + (size_t)(qtr * 64 + c) * HW + p0;
#pragma unroll
      for (int j = 0; j < 4; ++j)
        *(float4*)&xF[c * 68 + p0 + j * 4] = *(const float4*)(src + j * 4);
    }
    __syncthreads();
    {
      const int p = tid & 63;
      const int cb = tid >> 6;
#pragma unroll
      for (int jj = 0; jj < 2; ++jj) {
        const int c0 = (jj * 4 + cb) * 8;
        float t[8];
#pragma unroll
        for (int u = 0; u < 8; ++u) t[u] = xF[(c0 + u) * 68 + p];
        *(short8*)&xT[p * 264 + qtr * 64 + c0] = pack8(t);
      }
    }
  }
  __syncthreads();

  const int wave = tid >> 6;
  const int lane = tid & 63;
  const int lane16 = lane & 15;
  const int quad = lane >> 4;

  if (pj == 0) {
    floatx4 acc[2][4];
#pragma unroll
    for (int mt = 0; mt < 2; ++mt)
#pragma unroll
      for (int nf = 0; nf < 4; ++nf) acc[mt][nf] = (floatx4){0.f, 0.f, 0.f, 0.f};

#pragma unroll
    for (int ks = 0; ks < 8; ++ks) {
      short8 af[2];
#pragma unroll
      for (int mt = 0; mt < 2; ++mt)
        af[mt] = *(const short8*)&WqP[(size_t)((((ks * 4 + wave) * 2 + mt) * 64) + lane) * 8];
#pragma unroll
      for (int nf = 0; nf < 4; ++nf) {
        const short8 bf = *(const short8*)&xT[(nf * 16 + lane16) * 264 + ks * 32 + quad * 8];
#pragma unroll
        for (int mt = 0; mt < 2; ++mt) acc[mt][nf] = MFMA(af[mt], bf, acc[mt][nf]);
      }
    }

    float sc[2][4], off[2][4];
#pragma unroll
    for (int mt = 0; mt < 2; ++mt)
#pragma unroll
      for (int r = 0; r < 4; ++r) {
        const int o = wave * 32 + mt * 16 + quad * 4 + r;
        const float s = gq[o] * rsqrtf(vq[o] + BN_EPS) * SC2;
        sc[mt][r] = s;
        off[mt][r] = (bq[o] - mq[o]) * s + betaq[o] * SC2;
      }
#pragma unroll
    for (int nf = 0; nf < 4; ++nf) {
      const size_t prow = ((size_t)b * HW + pt * 64 + nf * 16 + lane16) * CK;
#pragma unroll
      for (int mt = 0; mt < 2; ++mt) {
        ushort4 pk;
        pk.x = f2bf(fmaxf(acc[mt][nf][0] * sc[mt][0] + off[mt][0], 0.f));
        pk.y = f2bf(fmaxf(acc[mt][nf][1] * sc[mt][1] + off[mt][1], 0.f));
        pk.z = f2bf(fmaxf(acc[mt][nf][2] * sc[mt][2] + off[mt][2], 0.f));
        pk.w = f2bf(fmaxf(acc[mt][nf][3] * sc[mt][3] + off[mt][3], 0.f));
        *(ushort4*)(Qb + prow + wave * 32 + mt * 16 + quad * 4) = pk;
      }
    }
  } else {
    const bool isK = (wave < 2);
    floatx4 acc[4][4];
#pragma unroll
    for (int mt = 0; mt < 4; ++mt)
#pragma unroll
      for (int nf = 0; nf < 4; ++nf) acc[mt][nf] = (floatx4){0.f, 0.f, 0.f, 0.f};

#pragma unroll
    for (int ks = 0; ks < 8; ++ks) {
      short8 af[4];
#pragma unroll
      for (int mt = 0; mt < 4; ++mt)
        af[mt] = *(const short8*)&WkvP[(size_t)((((ks * 4 + wave) * 4 + mt) * 64) + lane) * 8];
#pragma unroll
      for (int nf = 0; nf < 4; ++nf) {
        const short8 bf = *(const short8*)&xT[(nf * 16 + lane16) * 264 + ks * 32 + quad * 8];
#pragma unroll
        for (int mt = 0; mt < 4; ++mt) acc[mt][nf] = MFMA(af[mt], bf, acc[mt][nf]);
      }
    }

    if (isK) {
      float sc[4][4], off[4][4];
#pragma unroll
      for (int mt = 0; mt < 4; ++mt)
#pragma unroll
        for (int r = 0; r < 4; ++r) {
          const int o = wave * 64 + mt * 16 + quad * 4 + r;
          const float s = gk[o] * rsqrtf(vk[o] + BN_EPS);
          sc[mt][r] = s;
          off[mt][r] = (bk[o] - mk[o]) * s + betak[o];
        }
#pragma unroll
      for (int nf = 0; nf < 4; ++nf) {
        const size_t prow = ((size_t)b * HW + pt * 64 + nf * 16 + lane16) * CK;
#pragma unroll
        for (int mt = 0; mt < 4; ++mt) {
          ushort4 pk;
          pk.x = f2bf(fmaxf(acc[mt][nf][0] * sc[mt][0] + off[mt][0], 0.f));
          pk.y = f2bf(fmaxf(acc[mt][nf][1] * sc[mt][1] + off[mt][1], 0.f));
          pk.z = f2bf(fmaxf(acc[mt][nf][2] * sc[mt][2] + off[mt][2], 0.f));
          pk.w = f2bf(fmaxf(acc[mt][nf][3] * sc[mt][3] + off[mt][3], 0.f));
          *(ushort4*)(Kb + prow + wave * 64 + mt * 16 + quad * 4) = pk;
        }
      }
    } else {
#pragma unroll
      for (int mt = 0; mt < 4; ++mt) {
#pragma unroll
        for (int r = 0; r < 4; ++r) {
          const int c = wave * 64 + mt * 16 + quad * 4 + r - 128;
          const float bias = bv[c];
          unsigned short* dst = Vt + ((size_t)(b * CK + c)) * HW + pt * 64;
#pragma unroll
          for (int nf = 0; nf < 4; ++nf)
            dst[nf * 16 + lane16] = f2bf(acc[mt][nf][r] + bias);
        }
      }
    }
  }
}

// ---------------------------------------------------------------------------
// Kernel 2: split-K flash attention (round-5 structure) + XOR-swizzled P
// buffer (breaks the 8-way write conflict) + bf16 partial-O output.
// grid 128*NKC (b=blk&3, qt=(blk>>2)&31, kc=blk>>7), block 256 (4 waves).
// P col swizzle: store col ^ (quad<<4); read col ^ ((lane16>>2)<<4).
// Verified: write banks per (nf,r) land on disjoint octets {0,8,16,24};
// b128 reads stay 16B-contiguous (XOR only touches bits 4-5 of the col).
// ---------------------------------------------------------------------------
template<int NKC>
__global__ __launch_bounds__(256, 2) void attn_kernel8(
    const unsigned short* __restrict__ Qb, const unsigned short* __restrict__ Kb,
    const unsigned short* __restrict__ Vt, unsigned short* __restrict__ OpartH,
    float* __restrict__ Ml)
{
  constexpr int ITERS = 64 / NKC;
  const int tid = threadIdx.x;
  const int blk = blockIdx.x;
  const int b  = blk & 3;
  const int qt = (blk >> 2) & 31;
  const int kc = blk >> 7;

  const int wave = tid >> 6;
  const int lane = tid & 63;
  const int lane16 = lane & 15;
  const int quad = lane >> 4;

  __shared__ unsigned short Kl[64 * 136];    // [kp][c], stride 136
  __shared__ unsigned short Vl[128 * 72];    // [c][kp], stride 72
  __shared__ unsigned short Pl[4][32 * 72];  // per-wave [q][kp^swz], stride 72
  unsigned short* Pw = &Pl[wave][0];

  const int q0 = qt * 128 + wave * 32;
  short8 qf[2][4];
  {
    const unsigned short* Qs = Qb + ((size_t)b * HW + q0) * CK;
#pragma unroll
    for (int mt = 0; mt < 2; ++mt)
#pragma unroll
      for (int ks = 0; ks < 4; ++ks)
        qf[mt][ks] = *(const short8*)(Qs + (size_t)(mt * 16 + lane16) * CK + ks * 32 + quad * 8);
  }

  short8 ones;
#pragma unroll
  for (int i = 0; i < 8; ++i) ones[i] = (short)0x3F80;  // bf16 1.0

  floatx4 O[2][8];
  floatx4 Lacc[2];
#pragma unroll
  for (int mt = 0; mt < 2; ++mt) {
    Lacc[mt] = (floatx4){0.f, 0.f, 0.f, 0.f};
#pragma unroll
    for (int nf = 0; nf < 8; ++nf) O[mt][nf] = (floatx4){0.f, 0.f, 0.f, 0.f};
  }

  const int krow = tid >> 4;           // 0..15
  const int kcol = (tid & 15) * 8;     // shorts
  const int vrow = tid >> 1;           // 0..127 (channel)
  const int vcol = (tid & 1) * 32;     // shorts

  const unsigned short* Kg = Kb + (size_t)b * HW * CK + (size_t)(kc * ITERS * 64) * CK;
  const unsigned short* Vg = Vt + (size_t)b * CK * HW + kc * ITERS * 64;

  short8 kr[4], vr[4];
#pragma unroll
  for (int i2 = 0; i2 < 4; ++i2)
    kr[i2] = *(const short8*)(Kg + (size_t)(krow + i2 * 16) * CK + kcol);
#pragma unroll
  for (int i2 = 0; i2 < 4; ++i2)
    vr[i2] = *(const short8*)(Vg + (size_t)vrow * HW + vcol + i2 * 8);

  const int wswz = quad << 4;                 // P write-side column XOR
  const int rswz = (lane16 >> 2) << 4;        // P read-side column XOR

  for (int it = 0; it < ITERS; ++it) {
    __syncthreads();   // previous tile's LDS reads complete
#pragma unroll
    for (int i2 = 0; i2 < 4; ++i2)
      *(short8*)&Kl[(krow + i2 * 16) * 136 + kcol] = kr[i2];
#pragma unroll
    for (int i2 = 0; i2 < 4; ++i2)
      *(short8*)&Vl[vrow * 72 + vcol + i2 * 8] = vr[i2];
    __syncthreads();   // staging visible

    if (it + 1 < ITERS) {  // prefetch next tile into regs; overlaps compute
      const unsigned short* Kn = Kg + (size_t)((it + 1) * 64) * CK;
      const unsigned short* Vn = Vg + (it + 1) * 64;
#pragma unroll
      for (int i2 = 0; i2 < 4; ++i2)
        kr[i2] = *(const short8*)(Kn + (size_t)(krow + i2 * 16) * CK + kcol);
#pragma unroll
      for (int i2 = 0; i2 < 4; ++i2)
        vr[i2] = *(const short8*)(Vn + (size_t)vrow * HW + vcol + i2 * 8);
    }

    // S = Q K^T per 16-col tile, P = exp2(S) immediately (scale pre-folded)
#pragma unroll
    for (int nf = 0; nf < 4; ++nf) {
      floatx4 s0 = (floatx4){0.f, 0.f, 0.f, 0.f};
      floatx4 s1 = (floatx4){0.f, 0.f, 0.f, 0.f};
#pragma unroll
      for (int ks = 0; ks < 4; ++ks) {
        const short8 kf = *(const short8*)&Kl[(nf * 16 + lane16) * 136 + ks * 32 + quad * 8];
        s0 = MFMA(qf[0][ks], kf, s0);
        s1 = MFMA(qf[1][ks], kf, s1);
      }
      const int colw = (nf * 16 + lane16) ^ wswz;
#pragma unroll
      for (int r = 0; r < 4; ++r) {
        Pw[(quad * 4 + r) * 72 + colw] = f2bf(__builtin_amdgcn_exp2f(s0[r]));
        Pw[(16 + quad * 4 + r) * 72 + colw] = f2bf(__builtin_amdgcn_exp2f(s1[r]));
      }
    }
    __threadfence_block();  // order P ds_writes before cross-lane ds_reads

    // O += P V ; l += P * ones
#pragma unroll
    for (int ks = 0; ks < 2; ++ks) {
      const int colr = (ks * 32 + quad * 8) ^ rswz;
      const short8 pf0 = *(const short8*)&Pw[lane16 * 72 + colr];
      const short8 pf1 = *(const short8*)&Pw[(16 + lane16) * 72 + colr];
      Lacc[0] = MFMA(pf0, ones, Lacc[0]);
      Lacc[1] = MFMA(pf1, ones, Lacc[1]);
#pragma unroll
      for (int nf = 0; nf < 8; ++nf) {
        const short8 vf = *(const short8*)&Vl[(nf * 16 + lane16) * 72 + ks * 32 + quad * 8];
        O[0][nf] = MFMA(pf0, vf, O[0][nf]);
        O[1][nf] = MFMA(pf1, vf, O[1][nf]);
      }
    }
  }

  // epilogue: bf16 unnormalized partial O + fp32 l
  const int chunk = (b * 32 + qt) * NKC + kc;
  unsigned short* Op = OpartH + (size_t)chunk * (128 * 128);
#pragma unroll
  for (int mt = 0; mt < 2; ++mt)
#pragma unroll
    for (int nf = 0; nf < 8; ++nf)
#pragma unroll
      for (int r = 0; r < 4; ++r)
        Op[(size_t)(wave * 32 + mt * 16 + quad * 4 + r) * 128 + nf * 16 + lane16] =
            f2bf(O[mt][nf][r]);
  if (lane16 == 0) {
    float* Mp = Ml + (size_t)chunk * 128 + wave * 32;
#pragma unroll
    for (int mt = 0; mt < 2; ++mt)
#pragma unroll
      for (int r = 0; r < 4; ++r)
        Mp[mt * 16 + quad * 4 + r] = Lacc[mt][r];
  }
}

// ---------------------------------------------------------------------------
// Kernel 3: fused combine + out-projection (bf16 partials).
// grid (256 p-tiles of 16, 4 batch), block 256.
// ---------------------------------------------------------------------------
template<int NKC>
__global__ __launch_bounds__(256) void outproj_kernel(
    const unsigned short* __restrict__ OpartH, const float* __restrict__ Ml,
    const unsigned short* __restrict__ WoP, const float* __restrict__ bo,
    float* __restrict__ out)
{
  const int tid = threadIdx.x;
  const int pt = blockIdx.x;
  const int b  = blockIdx.y;
  const int qt = pt >> 3;
  const int q0 = (pt & 7) * 16;
  const int chunk0 = (b * 32 + qt) * NKC;

  __shared__ unsigned short Ctile[16 * 136];

  {
    const int row = tid >> 4;
    const int c8  = (tid & 15) * 8;
    float L = 0.f;
#pragma unroll
    for (int k = 0; k < NKC; ++k) L += Ml[(size_t)(chunk0 + k) * 128 + q0 + row];
    float acc[8];
#pragma unroll
    for (int i = 0; i < 8; ++i) acc[i] = 0.f;
#pragma unroll
    for (int k = 0; k < NKC; ++k) {
      const short8 v = *(const short8*)(OpartH + (size_t)(chunk0 + k) * 16384 +
                                        (size_t)(q0 + row) * 128 + c8);
#pragma unroll
      for (int i = 0; i < 8; ++i) acc[i] += bf2f((unsigned short)v[i]);
    }
    const float inv = 1.f / L;
#pragma unroll
    for (int i = 0; i < 8; ++i) acc[i] *= inv;
    *(short8*)&Ctile[row * 136 + c8] = pack8(acc);
  }
  __syncthreads();

  const int wave = tid >> 6;
  const int lane = tid & 63;
  const int lane16 = lane & 15;
  const int quad = lane >> 4;

  floatx4 acc[4];
#pragma unroll
  for (int mt = 0; mt < 4; ++mt) acc[mt] = (floatx4){0.f, 0.f, 0.f, 0.f};

#pragma unroll
  for (int ks = 0; ks < 4; ++ks) {
    const short8 bf = *(const short8*)&Ctile[lane16 * 136 + ks * 32 + quad * 8];
#pragma unroll
    for (int mt = 0; mt < 4; ++mt) {
      const short8 af = *(const short8*)&WoP[(size_t)((((ks * 4 + wave) * 4 + mt) * 64) + lane) * 8];
      acc[mt] = MFMA(af, bf, acc[mt]);
    }
  }

#pragma unroll
  for (int mt = 0; mt < 4; ++mt) {
#pragma unroll
    for (int r = 0; r < 4; ++r) {
      const int o = wave * 64 + mt * 16 + quad * 4 + r;
      float* dst = out + ((size_t)b * COUT + o) * HW + qt * 128 + q0;
      dst[lane16] = acc[mt][r] + bo[o];
    }
  }
}

extern "C" void kernel_launch(void* const* d_in, const int* in_sizes, int n_in,
                              void* d_out, int out_size, void* d_ws, size_t ws_size,
                              hipStream_t stream)
{
  (void)in_sizes; (void)n_in; (void)out_size;
  const float* x_enc = (const float*)d_in[0];
  const float* x_dec = (const float*)d_in[1];
  const float* wk    = (const float*)d_in[2];
  const float* bk    = (const float*)d_in[3];
  const float* gk    = (const float*)d_in[4];
  const float* betak = (const float*)d_in[5];
  const float* mk    = (const float*)d_in[6];
  const float* vk    = (const float*)d_in[7];
  const float* wq    = (const float*)d_in[8];
  const float* bq    = (const float*)d_in[9];
  const float* gq    = (const float*)d_in[10];
  const float* betaq = (const float*)d_in[11];
  const float* mq    = (const float*)d_in[12];
  const float* vq    = (const float*)d_in[13];
  const float* wv    = (const float*)d_in[14];
  const float* bv    = (const float*)d_in[15];
  const float* wo    = (const float*)d_in[16];
  const float* bo    = (const float*)d_in[17];
  float* out = (float*)d_out;

  const size_t qkv = (size_t)NB * HW * CK;  // elems per bf16 tensor
  unsigned short* WqP  = (unsigned short*)d_ws;      // 32768 shorts
  unsigned short* WkvP = WqP + 32768;                // 65536 shorts
  unsigned short* WoP  = WkvP + 65536;               // 32768 shorts
  unsigned short* Qb   = WoP + 32768;
  unsigned short* Kb   = Qb + qkv;
  unsigned short* Vt   = Kb + qkv;
  unsigned short* OpartH = Vt + qkv;                 // bf16 partials
  const size_t fixed_bytes = 131072 * 2 + 3 * qkv * 2;

  prep_kernel<<<dim3(64), 256, 0, stream>>>(wq, wk, wv, wo, WqP, WkvP, WoP);
  proj_kernel<<<dim3(64, 4, 2), 256, 0, stream>>>(
      x_enc, x_dec, WqP, WkvP,
      bq, gq, betaq, mq, vq, bk, gk, betak, mk, vk, bv, Qb, Kb, Vt);

  auto need = [&](int nkc) {
    return fixed_bytes + (size_t)128 * nkc * 16384 * 2      // OpartH bf16
                       + (size_t)128 * nkc * 128 * 4;       // Ml fp32
  };
  if (ws_size >= need(8)) {
    float* Ml = (float*)(OpartH + (size_t)128 * 8 * 16384);
    attn_kernel8<8><<<dim3(1024), 256, 0, stream>>>(Qb, Kb, Vt, OpartH, Ml);
    outproj_kernel<8><<<dim3(256, 4), 256, 0, stream>>>(OpartH, Ml, WoP, bo, out);
  } else if (ws_size >= need(4)) {
    float* Ml = (float*)(OpartH + (size_t)128 * 4 * 16384);
    attn_kernel8<4><<<dim3(512), 256, 0, stream>>>(Qb, Kb, Vt, OpartH, Ml);
    outproj_kernel<4><<<dim3(256, 4), 256, 0, stream>>>(OpartH, Ml, WoP, bo, out);
  } else if (ws_size >= need(2)) {
    float* Ml = (float*)(OpartH + (size_t)128 * 2 * 16384);
    attn_kernel8<2><<<dim3(256), 256, 0, stream>>>(Qb, Kb, Vt, OpartH, Ml);
    outproj_kernel<2><<<dim3(256, 4), 256, 0, stream>>>(OpartH, Ml, WoP, bo, out);
  } else {
    float* Ml = (float*)(OpartH + (size_t)128 * 1 * 16384);
    attn_kernel8<1><<<dim3(128), 256, 0, stream>>>(Qb, Kb, Vt, OpartH, Ml);
    outproj_kernel<1><<<dim3(256, 4), 256, 0, stream>>>(OpartH, Ml, WoP, bo, out);
  }
}